// Round 13
// baseline (215.911 us; speedup 1.0000x reference)
//
#include <hip/hip_runtime.h>
#include <hip/hip_fp16.h>

#define DIMQ 65536
#define BQ 128

typedef float v2f __attribute__((ext_vector_type(2)));

// ---------------------------------------------------------------------------
// CNOT ring as GF(2)-linear index permutation y = M x (verified R1-R6, absmax 0)
// ---------------------------------------------------------------------------
__host__ __device__ constexpr unsigned ring_map(unsigned x) {
  for (int bc = 15; bc >= 1; --bc) x ^= ((x >> bc) & 1u) << (bc - 1);
  x ^= (x & 1u) << 15;
  return x;
}
__host__ __device__ constexpr unsigned ring_unmap(unsigned y) {
  y ^= (y & 1u) << 15;
  for (int bc = 1; bc <= 15; ++bc) y ^= ((y >> bc) & 1u) << (bc - 1);
  return y;
}
__host__ __device__ constexpr unsigned row_of(int b) {
  return (b <= 14) ? ((0xFFFFu << b) & 0xFFFFu) : 0x7FFFu;
}
__host__ __device__ constexpr int popc16(unsigned v) {
  int c = 0; for (int i = 0; i < 16; ++i) c += (v >> i) & 1; return c;
}
static_assert(ring_unmap(ring_map(0x1234u)) == 0x1234u, "inv");
static_assert(ring_map(ring_unmap(0x5A5Au)) == 0x5A5Au, "inv");
__host__ __device__ constexpr bool check_rows() {
  const unsigned xs[4] = {0x1234u, 0x8001u, 0xFFFFu, 0x0F0Fu};
  for (int b = 0; b < 16; ++b)
    for (int i = 0; i < 4; ++i)
      if (((ring_map(xs[i]) >> b) & 1u) != (unsigned)(popc16(xs[i] & row_of(b)) & 1))
        return false;
  return true;
}
static_assert(check_rows(), "row_of = row b of M");
static_assert(ring_unmap(1u << 0)  == 0xC001u, "u0 = e0^e14^e15");
static_assert(ring_unmap(1u << 6)  == 0x0060u, "u6 = e5^e6");
static_assert(ring_unmap(1u << 11) == 0x0C00u, "u11 = e10^e11");
static_assert(ring_unmap(1u << 15) == 0xC000u, "u15 = e14^e15");
static_assert(ring_map(0x0C00u) == 0x0800u, "M(e10^e11)=e11");
static_assert(ring_map(0xC000u) == 0x8000u, "M(e14^e15)=e15");

// 13-bit local coords of the P3 block tile in z-space: z0..z11 + z15
__host__ __device__ constexpr unsigned loc13(unsigned z16) {
  return (z16 & 0x0FFFu) | (((z16 >> 15) & 1u) << 12);
}
__host__ __device__ constexpr unsigned sw13(unsigned i) { return i ^ ((i >> 5) & 31u); }

struct Tab32u { unsigned v[32]; };
__host__ __device__ constexpr Tab32u make_rx2() {
  Tab32u t{}; for (int r = 0; r < 32; ++r) t.v[r] = (unsigned)r << 11; return t;
}
__host__ __device__ constexpr Tab32u make_swrl() {
  Tab32u t{}; for (int r = 0; r < 32; ++r) t.v[r] = sw13(loc13(ring_map((unsigned)r)));
  return t;
}
__host__ __device__ constexpr Tab32u make_sw2() {
  Tab32u t{}; for (int r = 0; r < 32; ++r) t.v[r] = sw13((unsigned)r << 6);
  return t;
}
__host__ __device__ constexpr Tab32u make_rp3() {
  Tab32u t{}; for (int r = 0; r < 32; ++r) t.v[r] = (unsigned)r << 6; return t;
}
__host__ __device__ constexpr Tab32u make_t4() {
  Tab32u t{};
  for (int r = 0; r < 32; ++r) {
    unsigned r0 = r & 1, r1 = (r >> 1) & 1, r2 = (r >> 2) & 1, r3 = (r >> 3) & 1, r4 = (r >> 4) & 1;
    t.v[r] = (r0 << 10) | ((r0 ^ r1) << 11) | ((r1 ^ r2) << 12) |
             ((r2 ^ r3) << 13) | ((r3 ^ r4) << 14) | (r4 << 15);
  }
  return t;
}
__device__ constexpr Tab32u SWRL = make_swrl();
__device__ constexpr Tab32u SW2  = make_sw2();
__device__ constexpr Tab32u T4   = make_t4();

__host__ __device__ constexpr unsigned clmask(Tab32u t, unsigned row) {
  unsigned m = 0;
  for (int l = 0; l < 32; ++l)
    m |= (unsigned)(popc16(t.v[l] & row) & 1) << l;
  return m;
}
static_assert(clmask(make_t4(), 0xFFFFu) == 0u, "T4 chain has even parity");
static_assert(clmask(make_rx2(), row_of(1)) == 0x96696996u, "thue-morse parity of l");
// epilogue lane-mask structure (verified R2 on HW)
static_assert((row_of(6) & 63u) == 0u && (row_of(14) & 63u) == 0u, "plain-sum bits");
static_assert((row_of(5) & 63u) == 32u && (row_of(4) & 63u) == 48u, "chain lo");
static_assert((row_of(3) & 63u) == 56u && (row_of(2) & 63u) == 60u, "chain mid");
static_assert((row_of(1) & 63u) == 62u && (row_of(0) & 63u) == 63u, "chain hi");
static_assert((row_of(15) & 63u) == 63u, "bit15 mask");
// D1 varying-row structure
static_assert((row_of(0) & 31u) == 31u && (row_of(4) & 31u) == 16u, "suffix masks");
static_assert((row_of(5) & 31u) == 0u && (row_of(14) & 31u) == 0u, "rows 5..14 fixed");
static_assert((row_of(15) & 31u) == 31u, "row15 rides u0");
__host__ __device__ constexpr bool check_sufp() {
  for (unsigned r = 0; r < 32; ++r) {
    unsigned u = 0;
    for (int b = 0; b < 5; ++b) {
      unsigned s = 0; for (int j = b; j < 5; ++j) s ^= (r >> j) & 1;
      u |= s << b;
    }
    if ((u ^ (u >> 1)) != r) return false;
  }
  return true;
}
static_assert(check_sufp(), "suffix-parity inverse");

// ---------------------------------------------------------------------------
// Gate data: U = RZ(phi)@RY(theta) = D * R (verified R8 on HW).
// k_prep also zeroes the per-batch completion counters used by fused p4+head
// (same-stream ordering guarantees visibility before p4 runs).
// ---------------------------------------------------------------------------
__global__ void k_prep(const float* __restrict__ params, float* __restrict__ uc,
                       unsigned* __restrict__ cnt) {
  int g = threadIdx.x;
  if (g >= 64 && g < 192) cnt[g - 64] = 0u;
  if (g >= 48) return;
  float th = 0.5f * params[g * 2 + 0];
  float ph = 0.5f * params[g * 2 + 1];
  float st, ct, sp, cp;
  __sincosf(th, &st, &ct);
  __sincosf(ph, &sp, &cp);
  float* u = uc + g * 8;
  u[0] = ct; u[1] = st;
  u[2] = cp; u[3] = -sp;                 // v0 = e^{-i ph}
  u[4] = cp * cp - sp * sp;              // ratio = e^{+2i ph}
  u[5] = 2.f * sp * cp;
  u[6] = 0.f; u[7] = 0.f;
}

struct CS { float ct, st; };
__device__ inline CS load_cs(const float* __restrict__ uc, int d, int w) {
  const float* u = uc + (d * 16 + w) * 8;
  return {u[0], u[1]};
}
__device__ inline v2f ldV(const float* __restrict__ uc, int d, int w) {
  const float* u = uc + (d * 16 + w) * 8;
  v2f r; r.x = u[2]; r.y = u[3]; return r;
}
__device__ inline v2f ldR(const float* __restrict__ uc, int d, int w) {
  const float* u = uc + (d * 16 + w) * 8;
  v2f r; r.x = u[4]; r.y = u[5]; return r;
}

__device__ inline v2f splat(float s) { v2f r; r.x = s; r.y = s; return r; }
__device__ inline v2f conjv(v2f a) { v2f r; r.x = a.x; r.y = -a.y; return r; }
__device__ inline v2f dsel(bool c, v2f v) { return c ? conjv(v) : v; }

// cmul: c*a (complex), 2 VOP3P ops (HW-verified R8)
__device__ inline v2f cmul(v2f c, v2f a) {
  v2f t;
  asm("v_pk_mul_f32 %0, %1, %2 op_sel:[0,0] op_sel_hi:[0,1]"
      : "=v"(t) : "v"(c), "v"(a));
  asm("v_pk_fma_f32 %0, %1, %2, %0 op_sel:[1,1,0] op_sel_hi:[1,0,1] neg_lo:[0,1,0]"
      : "+v"(t) : "v"(c), "v"(a));
  return t;
}
// cmulc: conj(c)*a
__device__ inline v2f cmulc(v2f c, v2f a) {
  v2f t;
  asm("v_pk_mul_f32 %0, %1, %2 op_sel:[0,0] op_sel_hi:[0,1]"
      : "=v"(t) : "v"(c), "v"(a));
  asm("v_pk_fma_f32 %0, %1, %2, %0 op_sel:[1,1,0] op_sel_hi:[1,0,1] neg_hi:[0,1,0]"
      : "+v"(t) : "v"(c), "v"(a));
  return t;
}
// cmulr<H>: complex c times REAL scalar from half H of pk (HW-verified R8).
template <int H>
__device__ inline v2f cmulr(v2f c, v2f pk) {
  v2f t;
  if constexpr (H == 0)
    asm("v_pk_mul_f32 %0, %1, %2 op_sel:[0,0] op_sel_hi:[1,0]"
        : "=v"(t) : "v"(c), "v"(pk));
  else
    asm("v_pk_mul_f32 %0, %1, %2 op_sel:[0,1] op_sel_hi:[1,1]"
        : "=v"(t) : "v"(c), "v"(pk));
  return t;
}

__device__ inline v2f h_to_f2(float bits) {
  __half2 h = __builtin_bit_cast(__half2, bits);
  float2 f = __half22float2(h);
  v2f r; r.x = f.x; r.y = f.y;
  return r;
}
__device__ inline float f2_to_h(v2f v) {
  __half2 h = __float22half2_rn(make_float2(v.x, v.y));
  return __builtin_bit_cast(float, h);
}

template <int MASK>
__device__ inline float lane_xor_f(float v) {
  if constexpr (MASK == 1) {
    return __int_as_float(__builtin_amdgcn_update_dpp(
        0, __float_as_int(v), 0xB1, 0xF, 0xF, true));
  } else if constexpr (MASK == 2) {
    return __int_as_float(__builtin_amdgcn_update_dpp(
        0, __float_as_int(v), 0x4E, 0xF, 0xF, true));
  } else if constexpr (MASK == 3) {
    return __int_as_float(__builtin_amdgcn_update_dpp(
        0, __float_as_int(v), 0x1B, 0xF, 0xF, true));
  } else if constexpr (MASK < 32) {
    return __int_as_float(__builtin_amdgcn_ds_swizzle(
        __float_as_int(v), (MASK << 10) | 0x1F));
  } else {
    return __shfl_xor(v, MASK, 64);
  }
}
template <int MASK>
__device__ inline v2f lane_xor_v(v2f v) {
  v2f r; r.x = lane_xor_f<MASK>(v.x); r.y = lane_xor_f<MASK>(v.y);
  return r;
}

// Dual real-mix, interleaved: o0 = CT*A0 + S0*B0; o1 = CT*A1 + S1*B1.
__device__ inline void rmix2(v2f& o0, v2f CT, v2f S0_, v2f A0, v2f B0,
                             v2f& o1, v2f S1_, v2f A1, v2f B1) {
  v2f t0, t1;
  asm("v_pk_mul_f32 %0, %2, %3\n\t"
      "v_pk_mul_f32 %1, %5, %6\n\t"
      "v_pk_fma_f32 %0, %4, %7, %0\n\t"
      "v_pk_fma_f32 %1, %4, %8, %1"
      : "=&v"(t0), "=&v"(t1)
      : "v"(S0_), "v"(B0), "v"(CT), "v"(S1_), "v"(B1), "v"(A0), "v"(A1));
  o0 = t0; o1 = t1;
}

// Packed-bit REAL gate on two regs (HW-verified R8).
__device__ inline void pswap2(v2f& r0, v2f CT, v2f S, v2f A0, v2f& r1, v2f A1) {
  v2f t0, t1;
  asm("v_pk_mul_f32 %0, %2, %4 op_sel:[0,1] op_sel_hi:[1,0] neg_lo:[0,1]\n\t"
      "v_pk_mul_f32 %1, %2, %5 op_sel:[0,1] op_sel_hi:[1,0] neg_lo:[0,1]\n\t"
      "v_pk_fma_f32 %0, %3, %4, %0\n\t"
      "v_pk_fma_f32 %1, %3, %5, %1"
      : "=&v"(t0), "=&v"(t1)
      : "v"(S), "v"(CT), "v"(A0), "v"(A1));
  r0 = t0; r1 = t1;
}

// ---------------- real gates on 16 packed regs (layer 0) ----------------
__device__ inline void packed_gate16(v2f (&a)[16], CS u) {
  const v2f CT = splat(u.ct), S = splat(u.st);
#pragma unroll
  for (int l = 0; l < 16; l += 2)
    pswap2(a[l], CT, S, a[l], a[l + 1], a[l + 1]);
}

template <int K>
__device__ inline void pr_gate16(v2f (&a)[16], CS u) {
  const v2f CT = splat(u.ct), SP = splat(u.st), SN = splat(-u.st);
#pragma unroll
  for (int l = 0; l < 16; ++l) {
    if (l & (1 << K)) continue;
    const int p = l | (1 << K);
    const v2f A = a[l], B = a[p];
    rmix2(a[l], CT, SN, A, B,
          a[p],     SP, B, A);
  }
}

template <int MASK>
__device__ inline void lane_gate16(v2f (&a)[16], CS u, int lane) {
  const bool hi = (lane & MASK) != 0;
  const v2f CT = splat(u.ct), SS = splat(hi ? u.st : -u.st);
#pragma unroll
  for (int l = 0; l < 16; l += 2) {
    v2f p0 = lane_xor_v<MASK>(a[l]);
    v2f p1 = lane_xor_v<MASK>(a[l + 1]);
    rmix2(a[l],     CT, SS, a[l],     p0,
          a[l + 1],     SS, a[l + 1], p1);
  }
}

// ---------------- complex real-rotation gates (layers 1,2) ----------------
template <int MASK>
__device__ inline void lane_gate_sr(v2f (&a)[32], CS u, int hi) {
  const v2f CT = splat(u.ct), SS = splat(hi ? u.st : -u.st);
#pragma unroll
  for (int l = 0; l < 32; l += 2) {
    v2f p0 = lane_xor_v<MASK>(a[l]);
    v2f p1 = lane_xor_v<MASK>(a[l + 1]);
    rmix2(a[l],     CT, SS, a[l],     p0,
          a[l + 1],     SS, a[l + 1], p1);
  }
}

template <int PM, unsigned CLM>
__device__ inline void fused_reg_gate_r(v2f (&a)[32], CS u, unsigned xK,
                                        unsigned row) {
  const bool s = (__popc(xK & row) & 1) != 0;
  const v2f CT = splat(u.ct);
  const v2f S0 = splat(s ? u.st : -u.st), NS0 = splat(s ? -u.st : u.st);
  constexpr int LB = PM & (-PM);
#pragma unroll
  for (int l = 0; l < 32; ++l) {
    if (l & LB) continue;
    const int p = l ^ PM;
    const bool cl = (CLM >> l) & 1u;
    const v2f A = a[l], B = a[p];
    rmix2(a[l], CT, cl ? NS0 : S0, A, B,
          a[p],     cl ? S0 : NS0, B, A);
  }
}

template <int LM, unsigned CLM>
__device__ inline void fused_lane_gate_r(v2f (&a)[32], CS u, unsigned xK,
                                         unsigned row) {
  const bool s = (__popc(xK & row) & 1) != 0;
  const v2f CT = splat(u.ct);
  const v2f S0 = splat(s ? u.st : -u.st), NS0 = splat(s ? -u.st : u.st);
#pragma unroll
  for (int l = 0; l < 32; l += 2) {
    v2f p0 = lane_xor_v<LM>(a[l]);
    v2f p1 = lane_xor_v<LM>(a[l + 1]);
    const bool c0 = (CLM >> l) & 1u;
    const bool c1 = (CLM >> (l + 1)) & 1u;
    rmix2(a[l],     CT, c0 ? NS0 : S0, a[l],     p0,
          a[l + 1],     c1 ? NS0 : S0, a[l + 1], p1);
  }
}

template <int LM, int PM, unsigned CLM>
__device__ inline void fused_mixed_gate_r(v2f (&a)[32], CS u, unsigned xK,
                                          unsigned row) {
  const bool s = (__popc(xK & row) & 1) != 0;
  const v2f CT = splat(u.ct);
  const v2f S0 = splat(s ? u.st : -u.st), NS0 = splat(s ? -u.st : u.st);
  constexpr int LB = PM & (-PM);
#pragma unroll
  for (int l = 0; l < 32; ++l) {
    if (l & LB) continue;
    const int p = l ^ PM;
    const bool cl = (CLM >> l) & 1u;
    const bool cp = (CLM >> p) & 1u;
    const v2f A = a[l], B = a[p];
    v2f pa = lane_xor_v<LM>(B);
    v2f pb = lane_xor_v<LM>(A);
    rmix2(a[l], CT, cl ? NS0 : S0, A, pa,
          a[p],     cp ? NS0 : S0, B, pb);
  }
}

// ---------------------------------------------------------------------------
// Layer-0 diagonal + unpack (p2): 16 packed real regs -> 32 complex regs.
// ---------------------------------------------------------------------------
__device__ inline void apply_D0p(const v2f (&pk)[16], v2f (&a)[32],
                                 const float* __restrict__ uc, unsigned xK) {
  v2f c = dsel(xK & 1u, ldV(uc, 0, 15));
#pragma unroll
  for (int j = 1; j <= 10; ++j)
    c = cmul(dsel((xK >> j) & 1u, ldV(uc, 0, 15 - j)), c);
  v2f R[5];
#pragma unroll
  for (int k = 0; k < 5; ++k) {
    c = cmul(ldV(uc, 0, 4 - k), c);   // v(0) factors for bits 11..15
    R[k] = ldR(uc, 0, 4 - k);
  }
  a[0] = cmulr<0>(c, pk[0]);
#pragma unroll
  for (int i = 1; i < 32; ++i) {
    const int g = i ^ (i >> 1);
    const int k = __builtin_ctz((unsigned)i);
    const bool on = (g >> k) & 1;
    c = on ? cmul(R[k], c) : cmulc(R[k], c);
    a[g] = (g & 1) ? cmulr<1>(c, pk[g >> 1]) : cmulr<0>(c, pk[g >> 1]);
  }
}

// ---------------------------------------------------------------------------
// Layer-1 diagonal (p3; HW-verified R8).
// ---------------------------------------------------------------------------
__device__ inline void apply_D1(v2f (&a)[32], const float* __restrict__ uc,
                                unsigned xfull) {
  unsigned q = 0;
#pragma unroll
  for (int b = 0; b < 16; ++b)
    q |= (unsigned)(__popc(xfull & row_of(b)) & 1) << b;
  v2f c = dsel(q & 1u, ldV(uc, 1, 15));
#pragma unroll
  for (int b = 1; b < 16; ++b)
    c = cmul(dsel((q >> b) & 1u, ldV(uc, 1, 15 - b)), c);
  v2f RT[5];
#pragma unroll
  for (int b = 0; b < 5; ++b)
    RT[b] = dsel((q >> b) & 1u, ldR(uc, 1, 15 - b));
  RT[0] = cmul(dsel((q >> 15) & 1u, ldR(uc, 1, 0)), RT[0]);  // row 15 on u0
  a[0] = cmul(c, a[0]);
#pragma unroll
  for (int i = 1; i < 32; ++i) {
    const int u = i ^ (i >> 1);
    const int k = __builtin_ctz((unsigned)i);
    const bool on = (u >> k) & 1;
    c = on ? cmul(RT[k], c) : cmulc(RT[k], c);
    const int r = u ^ (u >> 1);
    a[r] = cmul(c, a[r]);
  }
}

// ---------------------------------------------------------------------------
// P1: L0 R-parts on x0..x10 (wires 15..5), REAL packed 2/reg. fp16-real out.
// ---------------------------------------------------------------------------
__global__ __launch_bounds__(256, 4)
void k_p1(const float* __restrict__ in, __half* __restrict__ dstb,
          const float* __restrict__ uc) {
  const int b = blockIdx.x >> 3;
  const unsigned hi = blockIdx.x & 7;
  const unsigned wg = threadIdx.x >> 6;
  const unsigned lane = threadIdx.x & 63;
  const unsigned xK = (hi << 13) | (wg << 11) | (lane << 2);
  const float* src = in + (size_t)b * DIMQ;
  v2f a[16];
#pragma unroll
  for (int c = 0; c < 8; ++c) {
    float4 q = *(const float4*)(src + xK + ((unsigned)c << 8));
    a[c * 2 + 0].x = q.x; a[c * 2 + 0].y = q.y;
    a[c * 2 + 1].x = q.z; a[c * 2 + 1].y = q.w;
  }
  packed_gate16(a, load_cs(uc, 0, 15));
  pr_gate16<0>(a, load_cs(uc, 0, 14));
  lane_gate16<1 >(a, load_cs(uc, 0, 13), lane);
  lane_gate16<2 >(a, load_cs(uc, 0, 12), lane);
  lane_gate16<4 >(a, load_cs(uc, 0, 11), lane);
  lane_gate16<8 >(a, load_cs(uc, 0, 10), lane);
  lane_gate16<16>(a, load_cs(uc, 0, 9 ), lane);
  lane_gate16<32>(a, load_cs(uc, 0, 8 ), lane);
  pr_gate16<1>(a, load_cs(uc, 0, 7));
  pr_gate16<2>(a, load_cs(uc, 0, 6));
  pr_gate16<3>(a, load_cs(uc, 0, 5));
  __half* dst = dstb + (size_t)b * DIMQ;
#pragma unroll
  for (int c = 0; c < 8; ++c) {
    float2 w;
    w.x = f2_to_h(a[c * 2 + 0]);
    w.y = f2_to_h(a[c * 2 + 1]);
    *(float2*)(dst + xK + ((unsigned)c << 8)) = w;
  }
}

// ---------------------------------------------------------------------------
// P2: L0 R wires 4..0 (REAL packed) + D0 unpack + fused L1 R. NATURAL store.
// ---------------------------------------------------------------------------
__global__ __launch_bounds__(256, 4)
void k_p2(const __half* __restrict__ srcb, __half2* __restrict__ dstb,
          const float* __restrict__ uc) {
  const int b = blockIdx.x >> 3;
  const unsigned t8 = blockIdx.x & 7;
  const unsigned wg = threadIdx.x >> 6;
  const unsigned lane = threadIdx.x & 63;
  const unsigned xK = (t8 << 8) | (wg << 6) | lane;
  const __half* src = srcb + (size_t)b * DIMQ;
  float* dst = (float*)(dstb + (size_t)b * DIMQ);
  v2f pk[16];
#pragma unroll
  for (int k = 0; k < 16; ++k) {
    pk[k].x = __half2float(src[((unsigned)(2 * k) << 11) | xK]);
    pk[k].y = __half2float(src[((unsigned)(2 * k + 1) << 11) | xK]);
  }
  packed_gate16(pk, load_cs(uc, 0, 4));
  pr_gate16<0>(pk, load_cs(uc, 0, 3));
  pr_gate16<1>(pk, load_cs(uc, 0, 2));
  pr_gate16<2>(pk, load_cs(uc, 0, 1));
  pr_gate16<3>(pk, load_cs(uc, 0, 0));
  v2f a[32];
  apply_D0p(pk, a, uc, xK);
  fused_lane_gate_r<3 , clmask(make_rx2(), row_of(1))>(a, load_cs(uc, 1, 14), xK, row_of(1));
  fused_lane_gate_r<6 , clmask(make_rx2(), row_of(2))>(a, load_cs(uc, 1, 13), xK, row_of(2));
  fused_lane_gate_r<12, clmask(make_rx2(), row_of(3))>(a, load_cs(uc, 1, 12), xK, row_of(3));
  fused_lane_gate_r<24, clmask(make_rx2(), row_of(4))>(a, load_cs(uc, 1, 11), xK, row_of(4));
  fused_lane_gate_r<48, clmask(make_rx2(), row_of(5))>(a, load_cs(uc, 1, 10), xK, row_of(5));
  fused_mixed_gate_r<1, 0x18, clmask(make_rx2(), 0xFFFFu)>(a, load_cs(uc, 1, 15), xK, 0xFFFFu);
  fused_reg_gate_r<3 , clmask(make_rx2(), row_of(12))>(a, load_cs(uc, 1, 3), xK, row_of(12));
  fused_reg_gate_r<6 , clmask(make_rx2(), row_of(13))>(a, load_cs(uc, 1, 2), xK, row_of(13));
  fused_reg_gate_r<12, clmask(make_rx2(), row_of(14))>(a, load_cs(uc, 1, 1), xK, row_of(14));
  fused_reg_gate_r<24, clmask(make_rx2(), row_of(15))>(a, load_cs(uc, 1, 0), xK, row_of(15));
#pragma unroll
  for (int r = 0; r < 32; ++r)
    dst[((unsigned)r << 11) | xK] = f2_to_h(a[r]);
}

// ---------------------------------------------------------------------------
// P3: L1 R rows 6..11 + D1 + LDS ring relabel + L2 R rows 1..10.
// (R9 structure: direct contiguous phase-1 load, single barrier.)
// ---------------------------------------------------------------------------
__global__ __launch_bounds__(256, 3)
void k_p3(const __half2* __restrict__ srcb, __half2* __restrict__ dstb,
          const float* __restrict__ uc) {
  __shared__ float lds[8192];
  const int b = blockIdx.x >> 3;
  const unsigned tb = blockIdx.x & 7;
  const unsigned x12 = tb & 1u, x13 = (tb >> 1) & 1u, tt = tb >> 2;
  const unsigned tid = threadIdx.x;
  const float* src = (const float*)(srcb + (size_t)b * DIMQ);
  float* dst = (float*)(dstb + (size_t)b * DIMQ);
  const unsigned lane = tid & 63u, wv = tid >> 6;
  const unsigned w0 = wv & 1u, w1 = wv >> 1;
  const unsigned g = (lane ^ (lane >> 1)) & 63u;
  const unsigned x5 = (lane ^ w0) & 1u;
  const unsigned xfull = (x5 << 5) | (g << 6) | (x12 << 12) | (x13 << 13)
                       | (w1 << 14) | ((w1 ^ tt) << 15);
  v2f a[32];
#pragma unroll
  for (unsigned k = 0; k < 8; ++k) {
    float4 q = *(const float4*)(src + xfull + 4u * k);  // 128B contiguous/thread
    a[4 * k + 0] = h_to_f2(q.x);
    a[4 * k + 1] = h_to_f2(q.y);
    a[4 * k + 2] = h_to_f2(q.z);
    a[4 * k + 3] = h_to_f2(q.w);
  }
  lane_gate_sr<1 >(a, load_cs(uc, 1, 9), __popc(xfull & row_of(6 )) & 1);
  lane_gate_sr<2 >(a, load_cs(uc, 1, 8), __popc(xfull & row_of(7 )) & 1);
  lane_gate_sr<4 >(a, load_cs(uc, 1, 7), __popc(xfull & row_of(8 )) & 1);
  lane_gate_sr<8 >(a, load_cs(uc, 1, 6), __popc(xfull & row_of(9 )) & 1);
  lane_gate_sr<16>(a, load_cs(uc, 1, 5), __popc(xfull & row_of(10)) & 1);
  lane_gate_sr<32>(a, load_cs(uc, 1, 4), __popc(xfull & row_of(11)) & 1);
  apply_D1(a, uc, xfull);
  const unsigned swzr = sw13(loc13(ring_map(xfull)));
#pragma unroll
  for (unsigned r = 0; r < 32; ++r) lds[swzr ^ SWRL.v[r]] = f2_to_h(a[r]);
  __syncthreads();
  const unsigned z12 = x12 ^ x13 ^ tt, z13 = x13 ^ tt, z14 = tt;
  const unsigned zloc2 = lane | (w0 << 11) | (w1 << 12);
  const unsigned sb2 = sw13(zloc2);
  const unsigned z16b = lane | (w0 << 11) | (z12 << 12) | (z13 << 13)
                      | (z14 << 14) | (w1 << 15);
#pragma unroll
  for (unsigned r = 0; r < 32; ++r) a[r] = h_to_f2(lds[sb2 ^ SW2.v[r]]);
  fused_lane_gate_r<3 , clmask(make_rp3(), row_of(1))>(a, load_cs(uc, 2, 14), z16b, row_of(1));
  fused_lane_gate_r<6 , clmask(make_rp3(), row_of(2))>(a, load_cs(uc, 2, 13), z16b, row_of(2));
  fused_lane_gate_r<12, clmask(make_rp3(), row_of(3))>(a, load_cs(uc, 2, 12), z16b, row_of(3));
  fused_lane_gate_r<24, clmask(make_rp3(), row_of(4))>(a, load_cs(uc, 2, 11), z16b, row_of(4));
  fused_lane_gate_r<48, clmask(make_rp3(), row_of(5))>(a, load_cs(uc, 2, 10), z16b, row_of(5));
  fused_mixed_gate_r<32, 1, clmask(make_rp3(), row_of(6))>(a, load_cs(uc, 2, 9), z16b, row_of(6));
  fused_reg_gate_r<3 , clmask(make_rp3(), row_of(7 ))>(a, load_cs(uc, 2, 8), z16b, row_of(7));
  fused_reg_gate_r<6 , clmask(make_rp3(), row_of(8 ))>(a, load_cs(uc, 2, 7), z16b, row_of(8));
  fused_reg_gate_r<12, clmask(make_rp3(), row_of(9 ))>(a, load_cs(uc, 2, 6), z16b, row_of(9));
  fused_reg_gate_r<24, clmask(make_rp3(), row_of(10))>(a, load_cs(uc, 2, 5), z16b, row_of(10));
#pragma unroll
  for (unsigned r = 0; r < 32; ++r)
    dst[z16b ^ (r << 6)] = f2_to_h(a[r]);
}

// ---------------------------------------------------------------------------
// P4: L2 R rows 11..15 + row 0; no layer-2 diagonal. Walsh epilogue (HW-ver.)
// + FUSED HEAD (R11): block reduces 4 waves in LDS -> 16-float block partial
// to global; last block per batch (threadfence-reduction pattern, counters
// zeroed by k_prep on the same stream) sums 8 block partials and applies the
// head dot-product. 1 counter-atomic per block (no data contention — NOT the
// R2 pattern of 4096 data-atomicAdds on 8 lines).
// ---------------------------------------------------------------------------
__device__ inline float rsum6(float s) {
  s += __shfl_xor(s, 1, 64);  s += __shfl_xor(s, 2, 64);
  s += __shfl_xor(s, 4, 64);  s += __shfl_xor(s, 8, 64);
  s += __shfl_xor(s, 16, 64); s += __shfl_xor(s, 32, 64);
  return s;
}
template <int NB>
__device__ inline float rsum_lo(float s) {
  if constexpr (NB >= 1) s += __shfl_xor(s, 1, 64);
  if constexpr (NB >= 2) s += __shfl_xor(s, 2, 64);
  if constexpr (NB >= 3) s += __shfl_xor(s, 4, 64);
  if constexpr (NB >= 4) s += __shfl_xor(s, 8, 64);
  if constexpr (NB >= 5) s += __shfl_xor(s, 16, 64);
  return s;
}

__global__ __launch_bounds__(256, 4)
void k_p4(const __half2* __restrict__ srcb, float* __restrict__ blockpart,
          const float* __restrict__ uc, const float* __restrict__ hw,
          const float* __restrict__ hb, unsigned* __restrict__ cnt,
          float* __restrict__ out) {
  const int b = blockIdx.x >> 3;
  const unsigned q = blockIdx.x & 7;
  const unsigned wg = threadIdx.x >> 6, lane = threadIdx.x & 63u;
  const unsigned zb = lane | ((wg & 1u) << 6) | ((wg >> 1) << 7) | ((q & 1u) << 8)
                    | (((q >> 1) & 1u) << 9) | ((q >> 2) << 10);
  const float* src = (const float*)(srcb + (size_t)b * DIMQ);
  v2f a[32];
#pragma unroll
  for (unsigned r = 0; r < 32; ++r) a[r] = h_to_f2(src[zb ^ T4.v[r]]);
  fused_reg_gate_r<1 , clmask(make_t4(), row_of(11))>(a, load_cs(uc, 2, 4), zb, row_of(11));
  fused_reg_gate_r<2 , clmask(make_t4(), row_of(12))>(a, load_cs(uc, 2, 3), zb, row_of(12));
  fused_reg_gate_r<4 , clmask(make_t4(), row_of(13))>(a, load_cs(uc, 2, 2), zb, row_of(13));
  fused_reg_gate_r<8 , clmask(make_t4(), row_of(14))>(a, load_cs(uc, 2, 1), zb, row_of(14));
  fused_reg_gate_r<16, clmask(make_t4(), row_of(15))>(a, load_cs(uc, 2, 0), zb, row_of(15));
  fused_mixed_gate_r<1, 16, clmask(make_t4(), 0xFFFFu)>(a, load_cs(uc, 2, 15), zb, 0xFFFFu);
  float s_tot = 0.f, s_b0 = 0.f, s_b1 = 0.f, s_b2 = 0.f, s_b3 = 0.f, s_b4 = 0.f;
#pragma unroll
  for (unsigned r = 0; r < 32; ++r) {
    const float p = fmaf(a[r].x, a[r].x, a[r].y * a[r].y);
    s_tot += p;
    s_b0 += (r & 1u)  ? -p : p;
    s_b1 += (r & 2u)  ? -p : p;
    s_b2 += (r & 4u)  ? -p : p;
    s_b3 += (r & 8u)  ? -p : p;
    s_b4 += (r & 16u) ? -p : p;
  }
  const float Rtot = rsum6(s_tot);
  const float Rb0 = rsum6(s_b0);
  const float Rb1 = rsum6(s_b1);
  const float Rb2 = rsum6(s_b2);
  const float Rb3 = rsum6(s_b3);
  const float c5      = s_tot  - __shfl_xor(s_tot,  32, 64);
  const float c45     = c5     - __shfl_xor(c5,     16, 64);
  const float c345    = c45    - __shfl_xor(c45,     8, 64);
  const float c2345   = c345   - __shfl_xor(c345,    4, 64);
  const float c12345  = c2345  - __shfl_xor(c2345,   2, 64);
  const float c012345 = c12345 - __shfl_xor(c12345,  1, 64);
  const float F32 = rsum_lo<5>(c5);
  const float F48 = rsum_lo<4>(c45);
  const float F56 = rsum_lo<3>(c345);
  const float F60 = rsum_lo<2>(c2345);
  const float F62 = rsum_lo<1>(c12345);
  const float F63t = c012345;
  float d = s_b4;
  d -= __shfl_xor(d, 32, 64); d -= __shfl_xor(d, 16, 64);
  d -= __shfl_xor(d,  8, 64); d -= __shfl_xor(d,  4, 64);
  d -= __shfl_xor(d,  2, 64); d -= __shfl_xor(d,  1, 64);
  const float F63b4 = d;
  __shared__ float part[4][16];
  __shared__ bool isLast;
  if (lane == 0) {
    const unsigned ybh = ring_map(zb & ~63u);
    const float V[16] = {F63b4, Rb3, Rb2, Rb1, Rb0,
                         Rtot, Rtot, Rtot, Rtot, Rtot,
                         F32, F48, F56, F60, F62, F63t};
#pragma unroll
    for (int w = 0; w < 16; ++w) {
      const int bit = 15 - w;
      part[wg][w] = ((ybh >> bit) & 1u) ? -V[w] : V[w];
    }
  }
  __syncthreads();
  const unsigned tid = threadIdx.x;
  if (tid < 16) {
    const float s = part[0][tid] + part[1][tid] + part[2][tid] + part[3][tid];
    blockpart[((size_t)b * 8 + q) * 16 + tid] = s;
  }
  __threadfence();       // release our block's partial before signaling
  __syncthreads();
  if (tid == 0) {
    const unsigned old = atomicAdd(&cnt[b], 1u);
    isLast = (old == 7u);
  }
  __syncthreads();
  if (isLast) {
    __threadfence();     // acquire: all 8 partials now visible
    if (tid < 16) {
      float f = 0.f;
      for (int j = 0; j < 8; ++j)
        f += blockpart[((size_t)b * 8 + j) * 16 + tid];
      part[0][tid] = f;
    }
    __syncthreads();
    if (tid == 0) {
      float o = hb[0];
#pragma unroll
      for (int w = 0; w < 16; ++w) o = fmaf(part[0][w], hw[w], o);
      out[b] = o;
    }
  }
}

extern "C" void kernel_launch(void* const* d_in, const int* in_sizes, int n_in,
                              void* d_out, int out_size, void* d_ws, size_t ws_size,
                              hipStream_t stream) {
  const float* state  = (const float*)d_in[0];   // (128, 65536) f32
  const float* params = (const float*)d_in[1];   // (3, 16, 2)   f32
  const float* head_w = (const float*)d_in[2];   // (1, 16)      f32
  const float* head_b = (const float*)d_in[3];   // (1,)         f32
  float* out = (float*)d_out;                    // (128,)       f32

  __half*  bufA = (__half*)d_ws;                           // 16 MB (real fp16)
  __half2* bufB = (__half2*)(bufA + (size_t)DIMQ * BQ);    // 32 MB
  __half2* bufC = bufB + (size_t)DIMQ * BQ;                // 32 MB
  float*   blockpart = (float*)(bufC + (size_t)DIMQ * BQ); // 128*8*16 f32
  unsigned* cnt = (unsigned*)(blockpart + (size_t)BQ * 8 * 16);  // 128 u32
  float*   uc = (float*)(cnt + 128);

  k_prep<<<dim3(1), dim3(192), 0, stream>>>(params, uc, cnt);

  const dim3 g(1024), blk(256);
  k_p1<<<g, blk, 0, stream>>>(state, bufA, uc);
  k_p2<<<g, blk, 0, stream>>>(bufA, bufB, uc);
  k_p3<<<g, blk, 0, stream>>>(bufB, bufC, uc);
  k_p4<<<g, blk, 0, stream>>>(bufC, blockpart, uc, head_w, head_b, cnt, out);
}

// Round 14
// 141.894 us; speedup vs baseline: 1.5216x; 1.5216x over previous
//
#include <hip/hip_runtime.h>
#include <hip/hip_fp16.h>

#define DIMQ 65536
#define BQ 128

typedef float v2f __attribute__((ext_vector_type(2)));

// ---------------------------------------------------------------------------
// CNOT ring as GF(2)-linear index permutation y = M x (verified R1-R6, absmax 0)
// NOTE (R12 lesson): do NOT fuse the head via __threadfence/last-block
// reduction — device-scope fences trigger per-XCD L2 writebacks (~65 us for
// 2048 fences), dwarfing the ~7 us saved launch. Separate k_head is optimal.
// ---------------------------------------------------------------------------
__host__ __device__ constexpr unsigned ring_map(unsigned x) {
  for (int bc = 15; bc >= 1; --bc) x ^= ((x >> bc) & 1u) << (bc - 1);
  x ^= (x & 1u) << 15;
  return x;
}
__host__ __device__ constexpr unsigned ring_unmap(unsigned y) {
  y ^= (y & 1u) << 15;
  for (int bc = 1; bc <= 15; ++bc) y ^= ((y >> bc) & 1u) << (bc - 1);
  return y;
}
__host__ __device__ constexpr unsigned row_of(int b) {
  return (b <= 14) ? ((0xFFFFu << b) & 0xFFFFu) : 0x7FFFu;
}
__host__ __device__ constexpr int popc16(unsigned v) {
  int c = 0; for (int i = 0; i < 16; ++i) c += (v >> i) & 1; return c;
}
static_assert(ring_unmap(ring_map(0x1234u)) == 0x1234u, "inv");
static_assert(ring_map(ring_unmap(0x5A5Au)) == 0x5A5Au, "inv");
__host__ __device__ constexpr bool check_rows() {
  const unsigned xs[4] = {0x1234u, 0x8001u, 0xFFFFu, 0x0F0Fu};
  for (int b = 0; b < 16; ++b)
    for (int i = 0; i < 4; ++i)
      if (((ring_map(xs[i]) >> b) & 1u) != (unsigned)(popc16(xs[i] & row_of(b)) & 1))
        return false;
  return true;
}
static_assert(check_rows(), "row_of = row b of M");
static_assert(ring_unmap(1u << 0)  == 0xC001u, "u0 = e0^e14^e15");
static_assert(ring_unmap(1u << 6)  == 0x0060u, "u6 = e5^e6");
static_assert(ring_unmap(1u << 11) == 0x0C00u, "u11 = e10^e11");
static_assert(ring_unmap(1u << 15) == 0xC000u, "u15 = e14^e15");
static_assert(ring_map(0x0C00u) == 0x0800u, "M(e10^e11)=e11");
static_assert(ring_map(0xC000u) == 0x8000u, "M(e14^e15)=e15");

// 13-bit local coords of the P3 block tile in z-space: z0..z11 + z15
__host__ __device__ constexpr unsigned loc13(unsigned z16) {
  return (z16 & 0x0FFFu) | (((z16 >> 15) & 1u) << 12);
}
__host__ __device__ constexpr unsigned sw13(unsigned i) { return i ^ ((i >> 5) & 31u); }

struct Tab32u { unsigned v[32]; };
__host__ __device__ constexpr Tab32u make_rx2() {
  Tab32u t{}; for (int r = 0; r < 32; ++r) t.v[r] = (unsigned)r << 11; return t;
}
__host__ __device__ constexpr Tab32u make_swrl() {
  Tab32u t{}; for (int r = 0; r < 32; ++r) t.v[r] = sw13(loc13(ring_map((unsigned)r)));
  return t;
}
__host__ __device__ constexpr Tab32u make_sw2() {
  Tab32u t{}; for (int r = 0; r < 32; ++r) t.v[r] = sw13((unsigned)r << 6);
  return t;
}
__host__ __device__ constexpr Tab32u make_rp3() {
  Tab32u t{}; for (int r = 0; r < 32; ++r) t.v[r] = (unsigned)r << 6; return t;
}
__host__ __device__ constexpr Tab32u make_t4() {
  Tab32u t{};
  for (int r = 0; r < 32; ++r) {
    unsigned r0 = r & 1, r1 = (r >> 1) & 1, r2 = (r >> 2) & 1, r3 = (r >> 3) & 1, r4 = (r >> 4) & 1;
    t.v[r] = (r0 << 10) | ((r0 ^ r1) << 11) | ((r1 ^ r2) << 12) |
             ((r2 ^ r3) << 13) | ((r3 ^ r4) << 14) | (r4 << 15);
  }
  return t;
}
__device__ constexpr Tab32u SWRL = make_swrl();
__device__ constexpr Tab32u SW2  = make_sw2();
__device__ constexpr Tab32u T4   = make_t4();

__host__ __device__ constexpr unsigned clmask(Tab32u t, unsigned row) {
  unsigned m = 0;
  for (int l = 0; l < 32; ++l)
    m |= (unsigned)(popc16(t.v[l] & row) & 1) << l;
  return m;
}
static_assert(clmask(make_t4(), 0xFFFFu) == 0u, "T4 chain has even parity");
static_assert(clmask(make_rx2(), row_of(1)) == 0x96696996u, "thue-morse parity of l");
// epilogue lane-mask structure (verified R2 on HW)
static_assert((row_of(6) & 63u) == 0u && (row_of(14) & 63u) == 0u, "plain-sum bits");
static_assert((row_of(5) & 63u) == 32u && (row_of(4) & 63u) == 48u, "chain lo");
static_assert((row_of(3) & 63u) == 56u && (row_of(2) & 63u) == 60u, "chain mid");
static_assert((row_of(1) & 63u) == 62u && (row_of(0) & 63u) == 63u, "chain hi");
static_assert((row_of(15) & 63u) == 63u, "bit15 mask");
// D1 varying-row structure
static_assert((row_of(0) & 31u) == 31u && (row_of(4) & 31u) == 16u, "suffix masks");
static_assert((row_of(5) & 31u) == 0u && (row_of(14) & 31u) == 0u, "rows 5..14 fixed");
static_assert((row_of(15) & 31u) == 31u, "row15 rides u0");
__host__ __device__ constexpr bool check_sufp() {
  for (unsigned r = 0; r < 32; ++r) {
    unsigned u = 0;
    for (int b = 0; b < 5; ++b) {
      unsigned s = 0; for (int j = b; j < 5; ++j) s ^= (r >> j) & 1;
      u |= s << b;
    }
    if ((u ^ (u >> 1)) != r) return false;
  }
  return true;
}
static_assert(check_sufp(), "suffix-parity inverse");

// ---------------------------------------------------------------------------
// Gate data: U = RZ(phi)@RY(theta) = D * R (verified R8 on HW).
// ---------------------------------------------------------------------------
__global__ void k_prep(const float* __restrict__ params, float* __restrict__ uc) {
  int g = threadIdx.x;
  if (g >= 48) return;
  float th = 0.5f * params[g * 2 + 0];
  float ph = 0.5f * params[g * 2 + 1];
  float st, ct, sp, cp;
  __sincosf(th, &st, &ct);
  __sincosf(ph, &sp, &cp);
  float* u = uc + g * 8;
  u[0] = ct; u[1] = st;
  u[2] = cp; u[3] = -sp;                 // v0 = e^{-i ph}
  u[4] = cp * cp - sp * sp;              // ratio = e^{+2i ph}
  u[5] = 2.f * sp * cp;
  u[6] = 0.f; u[7] = 0.f;
}

struct CS { float ct, st; };
__device__ inline CS load_cs(const float* __restrict__ uc, int d, int w) {
  const float* u = uc + (d * 16 + w) * 8;
  return {u[0], u[1]};
}
__device__ inline v2f ldV(const float* __restrict__ uc, int d, int w) {
  const float* u = uc + (d * 16 + w) * 8;
  v2f r; r.x = u[2]; r.y = u[3]; return r;
}
__device__ inline v2f ldR(const float* __restrict__ uc, int d, int w) {
  const float* u = uc + (d * 16 + w) * 8;
  v2f r; r.x = u[4]; r.y = u[5]; return r;
}

__device__ inline v2f splat(float s) { v2f r; r.x = s; r.y = s; return r; }
__device__ inline v2f conjv(v2f a) { v2f r; r.x = a.x; r.y = -a.y; return r; }
__device__ inline v2f dsel(bool c, v2f v) { return c ? conjv(v) : v; }

// cmul: c*a (complex), 2 VOP3P ops (HW-verified R8)
__device__ inline v2f cmul(v2f c, v2f a) {
  v2f t;
  asm("v_pk_mul_f32 %0, %1, %2 op_sel:[0,0] op_sel_hi:[0,1]"
      : "=v"(t) : "v"(c), "v"(a));
  asm("v_pk_fma_f32 %0, %1, %2, %0 op_sel:[1,1,0] op_sel_hi:[1,0,1] neg_lo:[0,1,0]"
      : "+v"(t) : "v"(c), "v"(a));
  return t;
}
// cmulc: conj(c)*a
__device__ inline v2f cmulc(v2f c, v2f a) {
  v2f t;
  asm("v_pk_mul_f32 %0, %1, %2 op_sel:[0,0] op_sel_hi:[0,1]"
      : "=v"(t) : "v"(c), "v"(a));
  asm("v_pk_fma_f32 %0, %1, %2, %0 op_sel:[1,1,0] op_sel_hi:[1,0,1] neg_hi:[0,1,0]"
      : "+v"(t) : "v"(c), "v"(a));
  return t;
}
// cmulr<H>: complex c times REAL scalar from half H of pk (HW-verified R8).
template <int H>
__device__ inline v2f cmulr(v2f c, v2f pk) {
  v2f t;
  if constexpr (H == 0)
    asm("v_pk_mul_f32 %0, %1, %2 op_sel:[0,0] op_sel_hi:[1,0]"
        : "=v"(t) : "v"(c), "v"(pk));
  else
    asm("v_pk_mul_f32 %0, %1, %2 op_sel:[0,1] op_sel_hi:[1,1]"
        : "=v"(t) : "v"(c), "v"(pk));
  return t;
}

__device__ inline v2f h_to_f2(float bits) {
  __half2 h = __builtin_bit_cast(__half2, bits);
  float2 f = __half22float2(h);
  v2f r; r.x = f.x; r.y = f.y;
  return r;
}
__device__ inline float f2_to_h(v2f v) {
  __half2 h = __float22half2_rn(make_float2(v.x, v.y));
  return __builtin_bit_cast(float, h);
}

template <int MASK>
__device__ inline float lane_xor_f(float v) {
  if constexpr (MASK == 1) {
    return __int_as_float(__builtin_amdgcn_update_dpp(
        0, __float_as_int(v), 0xB1, 0xF, 0xF, true));
  } else if constexpr (MASK == 2) {
    return __int_as_float(__builtin_amdgcn_update_dpp(
        0, __float_as_int(v), 0x4E, 0xF, 0xF, true));
  } else if constexpr (MASK == 3) {
    return __int_as_float(__builtin_amdgcn_update_dpp(
        0, __float_as_int(v), 0x1B, 0xF, 0xF, true));
  } else if constexpr (MASK < 32) {
    return __int_as_float(__builtin_amdgcn_ds_swizzle(
        __float_as_int(v), (MASK << 10) | 0x1F));
  } else {
    return __shfl_xor(v, MASK, 64);
  }
}
template <int MASK>
__device__ inline v2f lane_xor_v(v2f v) {
  v2f r; r.x = lane_xor_f<MASK>(v.x); r.y = lane_xor_f<MASK>(v.y);
  return r;
}

// Dual real-mix, interleaved: o0 = CT*A0 + S0*B0; o1 = CT*A1 + S1*B1.
__device__ inline void rmix2(v2f& o0, v2f CT, v2f S0_, v2f A0, v2f B0,
                             v2f& o1, v2f S1_, v2f A1, v2f B1) {
  v2f t0, t1;
  asm("v_pk_mul_f32 %0, %2, %3\n\t"
      "v_pk_mul_f32 %1, %5, %6\n\t"
      "v_pk_fma_f32 %0, %4, %7, %0\n\t"
      "v_pk_fma_f32 %1, %4, %8, %1"
      : "=&v"(t0), "=&v"(t1)
      : "v"(S0_), "v"(B0), "v"(CT), "v"(S1_), "v"(B1), "v"(A0), "v"(A1));
  o0 = t0; o1 = t1;
}

// Packed-bit REAL gate on two regs (HW-verified R8).
__device__ inline void pswap2(v2f& r0, v2f CT, v2f S, v2f A0, v2f& r1, v2f A1) {
  v2f t0, t1;
  asm("v_pk_mul_f32 %0, %2, %4 op_sel:[0,1] op_sel_hi:[1,0] neg_lo:[0,1]\n\t"
      "v_pk_mul_f32 %1, %2, %5 op_sel:[0,1] op_sel_hi:[1,0] neg_lo:[0,1]\n\t"
      "v_pk_fma_f32 %0, %3, %4, %0\n\t"
      "v_pk_fma_f32 %1, %3, %5, %1"
      : "=&v"(t0), "=&v"(t1)
      : "v"(S), "v"(CT), "v"(A0), "v"(A1));
  r0 = t0; r1 = t1;
}

// ---------------- real gates on 16 packed regs (layer 0) ----------------
__device__ inline void packed_gate16(v2f (&a)[16], CS u) {
  const v2f CT = splat(u.ct), S = splat(u.st);
#pragma unroll
  for (int l = 0; l < 16; l += 2)
    pswap2(a[l], CT, S, a[l], a[l + 1], a[l + 1]);
}

template <int K>
__device__ inline void pr_gate16(v2f (&a)[16], CS u) {
  const v2f CT = splat(u.ct), SP = splat(u.st), SN = splat(-u.st);
#pragma unroll
  for (int l = 0; l < 16; ++l) {
    if (l & (1 << K)) continue;
    const int p = l | (1 << K);
    const v2f A = a[l], B = a[p];
    rmix2(a[l], CT, SN, A, B,
          a[p],     SP, B, A);
  }
}

template <int MASK>
__device__ inline void lane_gate16(v2f (&a)[16], CS u, int lane) {
  const bool hi = (lane & MASK) != 0;
  const v2f CT = splat(u.ct), SS = splat(hi ? u.st : -u.st);
#pragma unroll
  for (int l = 0; l < 16; l += 2) {
    v2f p0 = lane_xor_v<MASK>(a[l]);
    v2f p1 = lane_xor_v<MASK>(a[l + 1]);
    rmix2(a[l],     CT, SS, a[l],     p0,
          a[l + 1],     SS, a[l + 1], p1);
  }
}

// ---------------- complex real-rotation gates (layers 1,2) ----------------
template <int MASK>
__device__ inline void lane_gate_sr(v2f (&a)[32], CS u, int hi) {
  const v2f CT = splat(u.ct), SS = splat(hi ? u.st : -u.st);
#pragma unroll
  for (int l = 0; l < 32; l += 2) {
    v2f p0 = lane_xor_v<MASK>(a[l]);
    v2f p1 = lane_xor_v<MASK>(a[l + 1]);
    rmix2(a[l],     CT, SS, a[l],     p0,
          a[l + 1],     SS, a[l + 1], p1);
  }
}

template <int PM, unsigned CLM>
__device__ inline void fused_reg_gate_r(v2f (&a)[32], CS u, unsigned xK,
                                        unsigned row) {
  const bool s = (__popc(xK & row) & 1) != 0;
  const v2f CT = splat(u.ct);
  const v2f S0 = splat(s ? u.st : -u.st), NS0 = splat(s ? -u.st : u.st);
  constexpr int LB = PM & (-PM);
#pragma unroll
  for (int l = 0; l < 32; ++l) {
    if (l & LB) continue;
    const int p = l ^ PM;
    const bool cl = (CLM >> l) & 1u;
    const v2f A = a[l], B = a[p];
    rmix2(a[l], CT, cl ? NS0 : S0, A, B,
          a[p],     cl ? S0 : NS0, B, A);
  }
}

template <int LM, unsigned CLM>
__device__ inline void fused_lane_gate_r(v2f (&a)[32], CS u, unsigned xK,
                                         unsigned row) {
  const bool s = (__popc(xK & row) & 1) != 0;
  const v2f CT = splat(u.ct);
  const v2f S0 = splat(s ? u.st : -u.st), NS0 = splat(s ? -u.st : u.st);
#pragma unroll
  for (int l = 0; l < 32; l += 2) {
    v2f p0 = lane_xor_v<LM>(a[l]);
    v2f p1 = lane_xor_v<LM>(a[l + 1]);
    const bool c0 = (CLM >> l) & 1u;
    const bool c1 = (CLM >> (l + 1)) & 1u;
    rmix2(a[l],     CT, c0 ? NS0 : S0, a[l],     p0,
          a[l + 1],     c1 ? NS0 : S0, a[l + 1], p1);
  }
}

template <int LM, int PM, unsigned CLM>
__device__ inline void fused_mixed_gate_r(v2f (&a)[32], CS u, unsigned xK,
                                          unsigned row) {
  const bool s = (__popc(xK & row) & 1) != 0;
  const v2f CT = splat(u.ct);
  const v2f S0 = splat(s ? u.st : -u.st), NS0 = splat(s ? -u.st : u.st);
  constexpr int LB = PM & (-PM);
#pragma unroll
  for (int l = 0; l < 32; ++l) {
    if (l & LB) continue;
    const int p = l ^ PM;
    const bool cl = (CLM >> l) & 1u;
    const bool cp = (CLM >> p) & 1u;
    const v2f A = a[l], B = a[p];
    v2f pa = lane_xor_v<LM>(B);
    v2f pb = lane_xor_v<LM>(A);
    rmix2(a[l], CT, cl ? NS0 : S0, A, pa,
          a[p],     cp ? NS0 : S0, B, pb);
  }
}

// ---------------------------------------------------------------------------
// Layer-0 diagonal + unpack (p2): 16 packed real regs -> 32 complex regs.
// ---------------------------------------------------------------------------
__device__ inline void apply_D0p(const v2f (&pk)[16], v2f (&a)[32],
                                 const float* __restrict__ uc, unsigned xK) {
  v2f c = dsel(xK & 1u, ldV(uc, 0, 15));
#pragma unroll
  for (int j = 1; j <= 10; ++j)
    c = cmul(dsel((xK >> j) & 1u, ldV(uc, 0, 15 - j)), c);
  v2f R[5];
#pragma unroll
  for (int k = 0; k < 5; ++k) {
    c = cmul(ldV(uc, 0, 4 - k), c);   // v(0) factors for bits 11..15
    R[k] = ldR(uc, 0, 4 - k);
  }
  a[0] = cmulr<0>(c, pk[0]);
#pragma unroll
  for (int i = 1; i < 32; ++i) {
    const int g = i ^ (i >> 1);
    const int k = __builtin_ctz((unsigned)i);
    const bool on = (g >> k) & 1;
    c = on ? cmul(R[k], c) : cmulc(R[k], c);
    a[g] = (g & 1) ? cmulr<1>(c, pk[g >> 1]) : cmulr<0>(c, pk[g >> 1]);
  }
}

// ---------------------------------------------------------------------------
// Layer-1 diagonal (p3; HW-verified R8).
// ---------------------------------------------------------------------------
__device__ inline void apply_D1(v2f (&a)[32], const float* __restrict__ uc,
                                unsigned xfull) {
  unsigned q = 0;
#pragma unroll
  for (int b = 0; b < 16; ++b)
    q |= (unsigned)(__popc(xfull & row_of(b)) & 1) << b;
  v2f c = dsel(q & 1u, ldV(uc, 1, 15));
#pragma unroll
  for (int b = 1; b < 16; ++b)
    c = cmul(dsel((q >> b) & 1u, ldV(uc, 1, 15 - b)), c);
  v2f RT[5];
#pragma unroll
  for (int b = 0; b < 5; ++b)
    RT[b] = dsel((q >> b) & 1u, ldR(uc, 1, 15 - b));
  RT[0] = cmul(dsel((q >> 15) & 1u, ldR(uc, 1, 0)), RT[0]);  // row 15 on u0
  a[0] = cmul(c, a[0]);
#pragma unroll
  for (int i = 1; i < 32; ++i) {
    const int u = i ^ (i >> 1);
    const int k = __builtin_ctz((unsigned)i);
    const bool on = (u >> k) & 1;
    c = on ? cmul(RT[k], c) : cmulc(RT[k], c);
    const int r = u ^ (u >> 1);
    a[r] = cmul(c, a[r]);
  }
}

// ---------------------------------------------------------------------------
// P1: L0 R-parts on x0..x10 (wires 15..5), REAL packed 2/reg. fp16-real out.
// ---------------------------------------------------------------------------
__global__ __launch_bounds__(256, 4)
void k_p1(const float* __restrict__ in, __half* __restrict__ dstb,
          const float* __restrict__ uc) {
  const int b = blockIdx.x >> 3;
  const unsigned hi = blockIdx.x & 7;
  const unsigned wg = threadIdx.x >> 6;
  const unsigned lane = threadIdx.x & 63;
  const unsigned xK = (hi << 13) | (wg << 11) | (lane << 2);
  const float* src = in + (size_t)b * DIMQ;
  v2f a[16];
#pragma unroll
  for (int c = 0; c < 8; ++c) {
    float4 q = *(const float4*)(src + xK + ((unsigned)c << 8));
    a[c * 2 + 0].x = q.x; a[c * 2 + 0].y = q.y;
    a[c * 2 + 1].x = q.z; a[c * 2 + 1].y = q.w;
  }
  packed_gate16(a, load_cs(uc, 0, 15));
  pr_gate16<0>(a, load_cs(uc, 0, 14));
  lane_gate16<1 >(a, load_cs(uc, 0, 13), lane);
  lane_gate16<2 >(a, load_cs(uc, 0, 12), lane);
  lane_gate16<4 >(a, load_cs(uc, 0, 11), lane);
  lane_gate16<8 >(a, load_cs(uc, 0, 10), lane);
  lane_gate16<16>(a, load_cs(uc, 0, 9 ), lane);
  lane_gate16<32>(a, load_cs(uc, 0, 8 ), lane);
  pr_gate16<1>(a, load_cs(uc, 0, 7));
  pr_gate16<2>(a, load_cs(uc, 0, 6));
  pr_gate16<3>(a, load_cs(uc, 0, 5));
  __half* dst = dstb + (size_t)b * DIMQ;
#pragma unroll
  for (int c = 0; c < 8; ++c) {
    float2 w;
    w.x = f2_to_h(a[c * 2 + 0]);
    w.y = f2_to_h(a[c * 2 + 1]);
    *(float2*)(dst + xK + ((unsigned)c << 8)) = w;
  }
}

// ---------------------------------------------------------------------------
// P2: L0 R wires 4..0 (REAL packed) + D0 unpack + fused L1 R. NATURAL store.
// ---------------------------------------------------------------------------
__global__ __launch_bounds__(256, 4)
void k_p2(const __half* __restrict__ srcb, __half2* __restrict__ dstb,
          const float* __restrict__ uc) {
  const int b = blockIdx.x >> 3;
  const unsigned t8 = blockIdx.x & 7;
  const unsigned wg = threadIdx.x >> 6;
  const unsigned lane = threadIdx.x & 63;
  const unsigned xK = (t8 << 8) | (wg << 6) | lane;
  const __half* src = srcb + (size_t)b * DIMQ;
  float* dst = (float*)(dstb + (size_t)b * DIMQ);
  v2f pk[16];
#pragma unroll
  for (int k = 0; k < 16; ++k) {
    pk[k].x = __half2float(src[((unsigned)(2 * k) << 11) | xK]);
    pk[k].y = __half2float(src[((unsigned)(2 * k + 1) << 11) | xK]);
  }
  packed_gate16(pk, load_cs(uc, 0, 4));
  pr_gate16<0>(pk, load_cs(uc, 0, 3));
  pr_gate16<1>(pk, load_cs(uc, 0, 2));
  pr_gate16<2>(pk, load_cs(uc, 0, 1));
  pr_gate16<3>(pk, load_cs(uc, 0, 0));
  v2f a[32];
  apply_D0p(pk, a, uc, xK);
  fused_lane_gate_r<3 , clmask(make_rx2(), row_of(1))>(a, load_cs(uc, 1, 14), xK, row_of(1));
  fused_lane_gate_r<6 , clmask(make_rx2(), row_of(2))>(a, load_cs(uc, 1, 13), xK, row_of(2));
  fused_lane_gate_r<12, clmask(make_rx2(), row_of(3))>(a, load_cs(uc, 1, 12), xK, row_of(3));
  fused_lane_gate_r<24, clmask(make_rx2(), row_of(4))>(a, load_cs(uc, 1, 11), xK, row_of(4));
  fused_lane_gate_r<48, clmask(make_rx2(), row_of(5))>(a, load_cs(uc, 1, 10), xK, row_of(5));
  fused_mixed_gate_r<1, 0x18, clmask(make_rx2(), 0xFFFFu)>(a, load_cs(uc, 1, 15), xK, 0xFFFFu);
  fused_reg_gate_r<3 , clmask(make_rx2(), row_of(12))>(a, load_cs(uc, 1, 3), xK, row_of(12));
  fused_reg_gate_r<6 , clmask(make_rx2(), row_of(13))>(a, load_cs(uc, 1, 2), xK, row_of(13));
  fused_reg_gate_r<12, clmask(make_rx2(), row_of(14))>(a, load_cs(uc, 1, 1), xK, row_of(14));
  fused_reg_gate_r<24, clmask(make_rx2(), row_of(15))>(a, load_cs(uc, 1, 0), xK, row_of(15));
#pragma unroll
  for (int r = 0; r < 32; ++r)
    dst[((unsigned)r << 11) | xK] = f2_to_h(a[r]);
}

// ---------------------------------------------------------------------------
// P3: L1 R rows 6..11 + D1 + LDS ring relabel + L2 R rows 1..10.
// (R9 structure: direct contiguous phase-1 load, single barrier.)
// ---------------------------------------------------------------------------
__global__ __launch_bounds__(256, 3)
void k_p3(const __half2* __restrict__ srcb, __half2* __restrict__ dstb,
          const float* __restrict__ uc) {
  __shared__ float lds[8192];
  const int b = blockIdx.x >> 3;
  const unsigned tb = blockIdx.x & 7;
  const unsigned x12 = tb & 1u, x13 = (tb >> 1) & 1u, tt = tb >> 2;
  const unsigned tid = threadIdx.x;
  const float* src = (const float*)(srcb + (size_t)b * DIMQ);
  float* dst = (float*)(dstb + (size_t)b * DIMQ);
  const unsigned lane = tid & 63u, wv = tid >> 6;
  const unsigned w0 = wv & 1u, w1 = wv >> 1;
  const unsigned g = (lane ^ (lane >> 1)) & 63u;
  const unsigned x5 = (lane ^ w0) & 1u;
  const unsigned xfull = (x5 << 5) | (g << 6) | (x12 << 12) | (x13 << 13)
                       | (w1 << 14) | ((w1 ^ tt) << 15);
  v2f a[32];
#pragma unroll
  for (unsigned k = 0; k < 8; ++k) {
    float4 q = *(const float4*)(src + xfull + 4u * k);  // 128B contiguous/thread
    a[4 * k + 0] = h_to_f2(q.x);
    a[4 * k + 1] = h_to_f2(q.y);
    a[4 * k + 2] = h_to_f2(q.z);
    a[4 * k + 3] = h_to_f2(q.w);
  }
  lane_gate_sr<1 >(a, load_cs(uc, 1, 9), __popc(xfull & row_of(6 )) & 1);
  lane_gate_sr<2 >(a, load_cs(uc, 1, 8), __popc(xfull & row_of(7 )) & 1);
  lane_gate_sr<4 >(a, load_cs(uc, 1, 7), __popc(xfull & row_of(8 )) & 1);
  lane_gate_sr<8 >(a, load_cs(uc, 1, 6), __popc(xfull & row_of(9 )) & 1);
  lane_gate_sr<16>(a, load_cs(uc, 1, 5), __popc(xfull & row_of(10)) & 1);
  lane_gate_sr<32>(a, load_cs(uc, 1, 4), __popc(xfull & row_of(11)) & 1);
  apply_D1(a, uc, xfull);
  const unsigned swzr = sw13(loc13(ring_map(xfull)));
#pragma unroll
  for (unsigned r = 0; r < 32; ++r) lds[swzr ^ SWRL.v[r]] = f2_to_h(a[r]);
  __syncthreads();
  const unsigned z12 = x12 ^ x13 ^ tt, z13 = x13 ^ tt, z14 = tt;
  const unsigned zloc2 = lane | (w0 << 11) | (w1 << 12);
  const unsigned sb2 = sw13(zloc2);
  const unsigned z16b = lane | (w0 << 11) | (z12 << 12) | (z13 << 13)
                      | (z14 << 14) | (w1 << 15);
#pragma unroll
  for (unsigned r = 0; r < 32; ++r) a[r] = h_to_f2(lds[sb2 ^ SW2.v[r]]);
  fused_lane_gate_r<3 , clmask(make_rp3(), row_of(1))>(a, load_cs(uc, 2, 14), z16b, row_of(1));
  fused_lane_gate_r<6 , clmask(make_rp3(), row_of(2))>(a, load_cs(uc, 2, 13), z16b, row_of(2));
  fused_lane_gate_r<12, clmask(make_rp3(), row_of(3))>(a, load_cs(uc, 2, 12), z16b, row_of(3));
  fused_lane_gate_r<24, clmask(make_rp3(), row_of(4))>(a, load_cs(uc, 2, 11), z16b, row_of(4));
  fused_lane_gate_r<48, clmask(make_rp3(), row_of(5))>(a, load_cs(uc, 2, 10), z16b, row_of(5));
  fused_mixed_gate_r<32, 1, clmask(make_rp3(), row_of(6))>(a, load_cs(uc, 2, 9), z16b, row_of(6));
  fused_reg_gate_r<3 , clmask(make_rp3(), row_of(7 ))>(a, load_cs(uc, 2, 8), z16b, row_of(7));
  fused_reg_gate_r<6 , clmask(make_rp3(), row_of(8 ))>(a, load_cs(uc, 2, 7), z16b, row_of(8));
  fused_reg_gate_r<12, clmask(make_rp3(), row_of(9 ))>(a, load_cs(uc, 2, 6), z16b, row_of(9));
  fused_reg_gate_r<24, clmask(make_rp3(), row_of(10))>(a, load_cs(uc, 2, 5), z16b, row_of(10));
#pragma unroll
  for (unsigned r = 0; r < 32; ++r)
    dst[z16b ^ (r << 6)] = f2_to_h(a[r]);
}

// ---------------------------------------------------------------------------
// P4: L2 R rows 11..15 + row 0; no layer-2 diagonal. Walsh epilogue (HW-ver.)
// Coalesced partials store; separate k_head (R12: fused head regressed 65 us
// from device-scope fence L2 writebacks — do not re-fuse).
// ---------------------------------------------------------------------------
__device__ inline float rsum6(float s) {
  s += __shfl_xor(s, 1, 64);  s += __shfl_xor(s, 2, 64);
  s += __shfl_xor(s, 4, 64);  s += __shfl_xor(s, 8, 64);
  s += __shfl_xor(s, 16, 64); s += __shfl_xor(s, 32, 64);
  return s;
}
template <int NB>
__device__ inline float rsum_lo(float s) {
  if constexpr (NB >= 1) s += __shfl_xor(s, 1, 64);
  if constexpr (NB >= 2) s += __shfl_xor(s, 2, 64);
  if constexpr (NB >= 3) s += __shfl_xor(s, 4, 64);
  if constexpr (NB >= 4) s += __shfl_xor(s, 8, 64);
  if constexpr (NB >= 5) s += __shfl_xor(s, 16, 64);
  return s;
}

__global__ __launch_bounds__(256, 4)
void k_p4(const __half2* __restrict__ srcb, float* __restrict__ partials,
          const float* __restrict__ uc) {
  const int b = blockIdx.x >> 3;
  const unsigned q = blockIdx.x & 7;
  const unsigned wg = threadIdx.x >> 6, lane = threadIdx.x & 63u;
  const unsigned zb = lane | ((wg & 1u) << 6) | ((wg >> 1) << 7) | ((q & 1u) << 8)
                    | (((q >> 1) & 1u) << 9) | ((q >> 2) << 10);
  const float* src = (const float*)(srcb + (size_t)b * DIMQ);
  v2f a[32];
#pragma unroll
  for (unsigned r = 0; r < 32; ++r) a[r] = h_to_f2(src[zb ^ T4.v[r]]);
  fused_reg_gate_r<1 , clmask(make_t4(), row_of(11))>(a, load_cs(uc, 2, 4), zb, row_of(11));
  fused_reg_gate_r<2 , clmask(make_t4(), row_of(12))>(a, load_cs(uc, 2, 3), zb, row_of(12));
  fused_reg_gate_r<4 , clmask(make_t4(), row_of(13))>(a, load_cs(uc, 2, 2), zb, row_of(13));
  fused_reg_gate_r<8 , clmask(make_t4(), row_of(14))>(a, load_cs(uc, 2, 1), zb, row_of(14));
  fused_reg_gate_r<16, clmask(make_t4(), row_of(15))>(a, load_cs(uc, 2, 0), zb, row_of(15));
  fused_mixed_gate_r<1, 16, clmask(make_t4(), 0xFFFFu)>(a, load_cs(uc, 2, 15), zb, 0xFFFFu);
  float s_tot = 0.f, s_b0 = 0.f, s_b1 = 0.f, s_b2 = 0.f, s_b3 = 0.f, s_b4 = 0.f;
#pragma unroll
  for (unsigned r = 0; r < 32; ++r) {
    const float p = fmaf(a[r].x, a[r].x, a[r].y * a[r].y);
    s_tot += p;
    s_b0 += (r & 1u)  ? -p : p;
    s_b1 += (r & 2u)  ? -p : p;
    s_b2 += (r & 4u)  ? -p : p;
    s_b3 += (r & 8u)  ? -p : p;
    s_b4 += (r & 16u) ? -p : p;
  }
  const float Rtot = rsum6(s_tot);
  const float Rb0 = rsum6(s_b0);
  const float Rb1 = rsum6(s_b1);
  const float Rb2 = rsum6(s_b2);
  const float Rb3 = rsum6(s_b3);
  const float c5      = s_tot  - __shfl_xor(s_tot,  32, 64);
  const float c45     = c5     - __shfl_xor(c5,     16, 64);
  const float c345    = c45    - __shfl_xor(c45,     8, 64);
  const float c2345   = c345   - __shfl_xor(c345,    4, 64);
  const float c12345  = c2345  - __shfl_xor(c2345,   2, 64);
  const float c012345 = c12345 - __shfl_xor(c12345,  1, 64);
  const float F32 = rsum_lo<5>(c5);
  const float F48 = rsum_lo<4>(c45);
  const float F56 = rsum_lo<3>(c345);
  const float F60 = rsum_lo<2>(c2345);
  const float F62 = rsum_lo<1>(c12345);
  const float F63t = c012345;
  float d = s_b4;
  d -= __shfl_xor(d, 32, 64); d -= __shfl_xor(d, 16, 64);
  d -= __shfl_xor(d,  8, 64); d -= __shfl_xor(d,  4, 64);
  d -= __shfl_xor(d,  2, 64); d -= __shfl_xor(d,  1, 64);
  const float F63b4 = d;
  if (lane == 0) {
    const unsigned ybh = ring_map(zb & ~63u);
    const float V[16] = {F63b4, Rb3, Rb2, Rb1, Rb0,
                         Rtot, Rtot, Rtot, Rtot, Rtot,
                         F32, F48, F56, F60, F62, F63t};
    const unsigned t = q * 4 + wg;
    float* dstp = partials + ((size_t)b * 32 + t) * 16;
#pragma unroll
    for (int w = 0; w < 16; ++w) {
      const int bit = 15 - w;
      dstp[w] = ((ybh >> bit) & 1u) ? -V[w] : V[w];
    }
  }
}

__global__ __launch_bounds__(256)
void k_head(const float* __restrict__ partials, const float* __restrict__ hw,
            const float* __restrict__ hb, float* __restrict__ out) {
  const int b = blockIdx.x;
  const int t = threadIdx.x;
  const int w = t & 15;
  const int i = t >> 4;
  float s = partials[((size_t)b * 32 + i) * 16 + w] +
            partials[((size_t)b * 32 + i + 16) * 16 + w];
  __shared__ float red[256];
  __shared__ float feats[16];
  red[t] = s;
  __syncthreads();
  if (t < 16) {
    float f = 0.f;
    for (int j = 0; j < 16; ++j) f += red[j * 16 + t];
    feats[t] = f;
  }
  __syncthreads();
  if (t == 0) {
    float o = hb[0];
    for (int w2 = 0; w2 < 16; ++w2) o = fmaf(feats[w2], hw[w2], o);
    out[b] = o;
  }
}

extern "C" void kernel_launch(void* const* d_in, const int* in_sizes, int n_in,
                              void* d_out, int out_size, void* d_ws, size_t ws_size,
                              hipStream_t stream) {
  const float* state  = (const float*)d_in[0];   // (128, 65536) f32
  const float* params = (const float*)d_in[1];   // (3, 16, 2)   f32
  const float* head_w = (const float*)d_in[2];   // (1, 16)      f32
  const float* head_b = (const float*)d_in[3];   // (1,)         f32
  float* out = (float*)d_out;                    // (128,)       f32

  __half*  bufA = (__half*)d_ws;                           // 16 MB (real fp16)
  __half2* bufB = (__half2*)(bufA + (size_t)DIMQ * BQ);    // 32 MB
  __half2* bufC = bufB + (size_t)DIMQ * BQ;                // 32 MB
  float*   partials = (float*)(bufC + (size_t)DIMQ * BQ);
  float*   uc = partials + (size_t)BQ * 32 * 16;

  k_prep<<<dim3(1), dim3(64), 0, stream>>>(params, uc);

  const dim3 g(1024), blk(256);
  k_p1<<<g, blk, 0, stream>>>(state, bufA, uc);
  k_p2<<<g, blk, 0, stream>>>(bufA, bufB, uc);
  k_p3<<<g, blk, 0, stream>>>(bufB, bufC, uc);
  k_p4<<<g, blk, 0, stream>>>(bufC, partials, uc);
  k_head<<<dim3(128), blk, 0, stream>>>(partials, head_w, head_b, out);
}